// Round 3
// baseline (11695.621 us; speedup 1.0000x reference)
//
#include <hip/hip_runtime.h>
#include <hip/hip_bf16.h>
#include <math.h>

// ---- problem dims ----
constexpr int NB   = 32;     // batch
constexpr int NS   = 256;    // seq len
constexpr int NLC  = 16;     // chars per word
constexpr int NWD  = 256;    // word dim
constexpr int NCD  = 124;    // char dim
constexpr int NCO  = 32;     // cnn out
constexpr int NPOS = 36;
constexpr int NENR = 7;
constexpr int NH   = 512;    // lstm hidden
constexpr int NT   = 18;     // tags
constexpr int NIN0 = 331;    // 256+36+32+7
constexpr int NIN0P= 336;    // padded to x16
constexpr int NIN1 = 1024;
constexpr int NBS  = NB*NS;  // 8192
constexpr int NG4  = 4*NH;   // 2048
constexpr int NHID = 128;
constexpr int NCHUNK = 32;   // unit-chunks per dir (16 units each)

typedef __attribute__((ext_vector_type(8))) short short8v;
typedef __attribute__((ext_vector_type(4))) float f32x4;

__device__ __forceinline__ float sigmoidf_(float x){ return 1.0f/(1.0f+expf(-x)); }
__device__ __forceinline__ short f2bf(float f) {
    union { __hip_bfloat16 h; short s; } u;
    u.h = __float2bfloat16(f);
    return u.s;
}
__device__ __forceinline__ float bf2f(short s) {
    union { unsigned u; float f; } v;
    v.u = ((unsigned)(unsigned short)s) << 16;
    return v.f;
}

// ---------------- features: word embed + char CNN + concat + relu ----------------
__global__ __launch_bounds__(128) void k_features(const int* __restrict__ x_word,
    const float* __restrict__ x_pos, const int* __restrict__ x_char,
    const float* __restrict__ x_enr, const float* __restrict__ wembW,
    const float* __restrict__ cembW, const float* __restrict__ cnnW,
    const float* __restrict__ cnnb, float* __restrict__ xout)
{
    __shared__ float ce[NLC][NCD];
    __shared__ float cv[NCO][13];
    __shared__ float cpool[NCO];
    int n = blockIdx.x;
    int tid = threadIdx.x;
    for (int i = tid; i < NLC*NCD; i += 128) {
        int l = i / NCD, c = i % NCD;
        ce[l][c] = cembW[x_char[n*NLC + l]*NCD + c];
    }
    __syncthreads();
    for (int p = tid; p < NCO*12; p += 128) {
        int o = p & 31, t = p >> 5;
        const float* wr = cnnW + o*NCD*5;
        float acc = 0.f;
        for (int c = 0; c < NCD; c++) {
            #pragma unroll
            for (int k = 0; k < 5; k++) acc += ce[t+k][c] * wr[c*5+k];
        }
        cv[o][t] = acc;
    }
    __syncthreads();
    if (tid < NCO) {
        float m = cv[tid][0];
        #pragma unroll
        for (int t = 1; t < 12; t++) m = fmaxf(m, cv[tid][t]);
        cpool[tid] = m + cnnb[tid];
    }
    __syncthreads();
    int widx = x_word[n];
    float* xr = xout + (size_t)n * NIN0P;
    for (int j = tid; j < NIN0P; j += 128) {
        float v;
        if (j < NWD)            v = wembW[(size_t)widx*NWD + j];
        else if (j < NWD+NPOS)  v = x_pos[n*NPOS + (j-NWD)];
        else if (j < NWD+NPOS+NCO) v = cpool[j-(NWD+NPOS)];
        else if (j < NIN0)      v = x_enr[n*NENR + (j-(NWD+NPOS+NCO))];
        else                    v = 0.f;   // K pad
        xr[j] = fmaxf(v, 0.f);
    }
}

// ---------------- pad layer-0 Wih from K=331 to K=336 (zero tail) ----------------
__global__ void k_pad_wih(const float* __restrict__ Wf, const float* __restrict__ Wb,
                          float* __restrict__ Pf, float* __restrict__ Pb)
{
    const float* Wsrc = blockIdx.y ? Wb : Wf;
    float* Pdst = blockIdx.y ? Pb : Pf;
    int i = blockIdx.x*256 + threadIdx.x;
    if (i < NG4*NIN0P) {
        int r = i / NIN0P, c = i % NIN0P;
        Pdst[i] = (c < NIN0) ? Wsrc[r*NIN0 + c] : 0.f;
    }
}

// ---------------- f32 GEMM: C[M,N] = A[M,K] @ W[N,K]^T + bias[N] ----------------
constexpr int GBM = 128, GBN = 128, GBK = 16;
__global__ __launch_bounds__(256) void k_gemm(const float* __restrict__ A,
    const float* __restrict__ W, const float* __restrict__ bias,
    float* __restrict__ C, int M, int N, int K)
{
    __shared__ float As[GBK][GBM+4];
    __shared__ float Bs[GBK][GBN+4];
    int bm = blockIdx.x * GBM, bn = blockIdx.y * GBN;
    int tid = threadIdx.x;
    int tm = (tid & 15) * 8, tn = (tid >> 4) * 8;
    float acc[8][8] = {};
    for (int k0 = 0; k0 < K; k0 += GBK) {
        #pragma unroll
        for (int ii = 0; ii < 2; ii++) {
            int idx = tid + 256*ii;
            int m = idx >> 2, kj = (idx & 3) * 4;
            float4 va = *(const float4*)(A + (size_t)(bm+m)*K + k0 + kj);
            As[kj+0][m] = va.x; As[kj+1][m] = va.y; As[kj+2][m] = va.z; As[kj+3][m] = va.w;
            float4 vb = *(const float4*)(W + (size_t)(bn+m)*K + k0 + kj);
            Bs[kj+0][m] = vb.x; Bs[kj+1][m] = vb.y; Bs[kj+2][m] = vb.z; Bs[kj+3][m] = vb.w;
        }
        __syncthreads();
        #pragma unroll
        for (int k = 0; k < GBK; k++) {
            float a[8], b[8];
            *(float4*)&a[0] = *(const float4*)&As[k][tm];
            *(float4*)&a[4] = *(const float4*)&As[k][tm+4];
            *(float4*)&b[0] = *(const float4*)&Bs[k][tn];
            *(float4*)&b[4] = *(const float4*)&Bs[k][tn+4];
            #pragma unroll
            for (int i = 0; i < 8; i++)
                #pragma unroll
                for (int j = 0; j < 8; j++)
                    acc[i][j] += a[i]*b[j];
        }
        __syncthreads();
    }
    #pragma unroll
    for (int i = 0; i < 8; i++) {
        float4 o0, o1;
        o0.x = acc[i][0]+bias[bn+tn+0]; o0.y = acc[i][1]+bias[bn+tn+1];
        o0.z = acc[i][2]+bias[bn+tn+2]; o0.w = acc[i][3]+bias[bn+tn+3];
        o1.x = acc[i][4]+bias[bn+tn+4]; o1.y = acc[i][5]+bias[bn+tn+5];
        o1.z = acc[i][6]+bias[bn+tn+6]; o1.w = acc[i][7]+bias[bn+tn+7];
        *(float4*)(C + (size_t)(bm+tm+i)*N + bn+tn)   = o0;
        *(float4*)(C + (size_t)(bm+tm+i)*N + bn+tn+4) = o1;
    }
}

// ---------------- persistent LSTM layer (both dirs), weight-stationary MFMA ----
// grid (NCHUNK=32, 2 dirs) = 64 blocks, 256 threads (4 waves = 4 gates).
// Split-bf16 (bf16x3) recurrent matvec: h = h_hi + h_lo, W = w_hi + w_lo;
// z ~= h_hi*w_hi + h_lo*w_hi + h_hi*w_lo  (error ~2^-18, vs 2^-9 plain bf16).
// Cross-chunk sync: device-scope counter per (dir, t); acquire-load emits L1 inv.
__global__ __launch_bounds__(256) void k_lstm_layer(
    const float* __restrict__ zx_f, const float* __restrict__ zx_b,
    const float* __restrict__ Whh_f, const float* __restrict__ Whh_b,
    float* __restrict__ hcat, unsigned short* __restrict__ hbf,
    unsigned* __restrict__ flags)
{
    int chunk = blockIdx.x;        // 0..31 (16 hidden units each)
    int dir   = blockIdx.y;
    int tid = threadIdx.x;
    int w  = tid >> 6;             // wave index = gate index (i,f,g,o)
    int l  = tid & 63;
    int lr = l & 15, lk = l >> 4;
    const float* zx  = dir ? zx_b  : zx_f;
    const float* Whh = dir ? Whh_b : Whh_f;
    // hb layout: [dir][slot 0/1][plane hi/lo][NB*NH]
    unsigned short* hb = hbf + (size_t)dir * (4*NB*NH);
    unsigned* flag = flags + (size_t)dir * NS * 16;   // 64B stride per step

    // ---- preload this wave's Whh slice into registers, split hi/lo bf16 ----
    short8v bwh[16], bwl[16];
    {
        const float* wrow = Whh + ((size_t)(w*NH + chunk*16 + lr))*NH + lk*8;
        #pragma unroll
        for (int kt = 0; kt < 16; kt++) {
            float u[8];
            *(float4*)&u[0] = *(const float4*)(wrow + kt*32);
            *(float4*)&u[4] = *(const float4*)(wrow + kt*32 + 4);
            short8v sh, sl;
            #pragma unroll
            for (int j = 0; j < 8; j++) {
                short hi = f2bf(u[j]);
                sh[j] = hi;
                sl[j] = f2bf(u[j] - bf2f(hi));
            }
            bwh[kt] = sh; bwl[kt] = sl;
        }
    }
    __shared__ float zsh[4][NB][16];
    float c0 = 0.f, c1 = 0.f;      // cell state: cells tid and tid+256

    for (int t = 0; t < NS; t++) {
        int t_eff = dir ? (NS-1-t) : t;
        f32x4 acc0 = {0.f,0.f,0.f,0.f};
        f32x4 acc1 = {0.f,0.f,0.f,0.f};
        if (t > 0) {
            if (tid == 0) {
                while (__hip_atomic_load(&flag[(t-1)*16], __ATOMIC_ACQUIRE,
                                         __HIP_MEMORY_SCOPE_AGENT) < (unsigned)NCHUNK) {}
            }
            __syncthreads();
            const short* hph = (const short*)(hb + ((t-1)&1)*(2*NB*NH));  // hi plane
            const short* hpl = hph + NB*NH;                               // lo plane
            #pragma unroll
            for (int kt = 0; kt < 16; kt++) {
                int o0 = (size_t)lr*NH      + kt*32 + lk*8;
                int o1 = (size_t)(16+lr)*NH + kt*32 + lk*8;
                short8v a0h = *(const short8v*)(hph + o0);
                short8v a0l = *(const short8v*)(hpl + o0);
                short8v a1h = *(const short8v*)(hph + o1);
                short8v a1l = *(const short8v*)(hpl + o1);
                acc0 = __builtin_amdgcn_mfma_f32_16x16x32_bf16(a0h, bwh[kt], acc0, 0, 0, 0);
                acc0 = __builtin_amdgcn_mfma_f32_16x16x32_bf16(a0l, bwh[kt], acc0, 0, 0, 0);
                acc0 = __builtin_amdgcn_mfma_f32_16x16x32_bf16(a0h, bwl[kt], acc0, 0, 0, 0);
                acc1 = __builtin_amdgcn_mfma_f32_16x16x32_bf16(a1h, bwh[kt], acc1, 0, 0, 0);
                acc1 = __builtin_amdgcn_mfma_f32_16x16x32_bf16(a1l, bwh[kt], acc1, 0, 0, 0);
                acc1 = __builtin_amdgcn_mfma_f32_16x16x32_bf16(a1h, bwl[kt], acc1, 0, 0, 0);
            }
        }
        // C layout: col = lane&15 (unit), row = (lane>>4)*4+j (batch)
        #pragma unroll
        for (int j = 0; j < 4; j++) {
            zsh[w][lk*4+j][lr]    = acc0[j];
            zsh[w][16+lk*4+j][lr] = acc1[j];
        }
        __syncthreads();
        // ---- epilogue: 512 (batch,unit) cells / 256 threads ----
        #pragma unroll
        for (int cc = 0; cc < 2; cc++) {
            int cell = tid + cc*256, b = cell >> 4, u = cell & 15;
            const float* zr = zx + ((size_t)(b*NS + t_eff))*NG4 + chunk*16 + u;
            float zi = zr[0]      + zsh[0][b][u];
            float zf = zr[NH]     + zsh[1][b][u];
            float zg = zr[2*NH]   + zsh[2][b][u];
            float zo = zr[3*NH]   + zsh[3][b][u];
            float cold = cc ? c1 : c0;
            float cn = sigmoidf_(zf)*cold + sigmoidf_(zi)*tanhf(zg);
            float hn = sigmoidf_(zo)*tanhf(cn);
            if (cc) c1 = cn; else c0 = cn;
            hcat[((size_t)(b*NS + t_eff))*NIN1 + dir*NH + chunk*16 + u] = hn;
            short hi = f2bf(hn);
            short lo = f2bf(hn - bf2f(hi));
            size_t slot = (size_t)(t&1)*(2*NB*NH) + b*NH + chunk*16 + u;
            hb[slot]         = (unsigned short)hi;
            hb[slot + NB*NH] = (unsigned short)lo;
        }
        __threadfence();
        __syncthreads();
        if (tid == 0)
            __hip_atomic_fetch_add(&flag[t*16], 1u, __ATOMIC_RELEASE,
                                   __HIP_MEMORY_SCOPE_AGENT);
    }
}

// ---------------- emissions: em = hid1 @ lin2W^T + b2 ----------------
__global__ __launch_bounds__(256) void k_lin2(const float* __restrict__ hid,
    const float* __restrict__ W2, const float* __restrict__ b2, float* __restrict__ em)
{
    int flat = blockIdx.x*256 + threadIdx.x;
    if (flat >= NBS*NT) return;
    int m = flat / NT, j = flat % NT;
    const float* hr = hid + (size_t)m*NHID;
    const float* wr = W2 + j*NHID;
    float acc = b2[j];
    #pragma unroll 8
    for (int k = 0; k < NHID; k += 4) {
        float4 h4 = *(const float4*)(hr+k);
        float4 w4 = *(const float4*)(wr+k);
        acc += h4.x*w4.x + h4.y*w4.y + h4.z*w4.z + h4.w*w4.w;
    }
    em[flat] = acc;
}

// ---------------- viterbi decode (one wave per batch item) ----------------
__global__ __launch_bounds__(64) void k_viterbi(const float* __restrict__ em,
    const float* __restrict__ start, const float* __restrict__ endv,
    const float* __restrict__ trans, float* __restrict__ dec)
{
    __shared__ float sc[NT];
    __shared__ float tr[NT][NT];
    __shared__ unsigned char hist[NS][NT];
    int b = blockIdx.x, tid = threadIdx.x;
    for (int i = tid; i < NT*NT; i += 64) tr[i/NT][i%NT] = trans[i];
    if (tid < NT) sc[tid] = start[tid] + em[((size_t)b*NS)*NT + tid];
    __syncthreads();
    for (int t = 1; t < NS; t++) {
        float best = -1e30f; int bi = 0;
        if (tid < NT) {
            for (int i = 0; i < NT; i++) {
                float v = sc[i] + tr[i][tid];
                if (v > best) { best = v; bi = i; }
            }
            hist[t][tid] = (unsigned char)bi;
            best += em[((size_t)b*NS + t)*NT + tid];
        }
        __syncthreads();
        if (tid < NT) sc[tid] = best;
        __syncthreads();
    }
    if (tid == 0) {
        float bv = sc[0] + endv[0]; int tag = 0;
        for (int j = 1; j < NT; j++) { float v = sc[j] + endv[j]; if (v > bv) { bv = v; tag = j; } }
        dec[b*NS + NS-1] = (float)tag;
        for (int t = NS-1; t >= 1; t--) { tag = hist[t][tag]; dec[b*NS + t-1] = (float)tag; }
    }
}

// ---------------- CRF NLL (mask is all ones) ----------------
__global__ __launch_bounds__(64) void k_nll(const float* __restrict__ em,
    const int* __restrict__ tags, const float* __restrict__ start,
    const float* __restrict__ endv, const float* __restrict__ trans,
    float* __restrict__ partial)
{
    __shared__ float sc[NT];
    __shared__ float tr[NT][NT];
    int b = blockIdx.x, tid = threadIdx.x;
    for (int i = tid; i < NT*NT; i += 64) tr[i/NT][i%NT] = trans[i];
    if (tid < NT) sc[tid] = start[tid] + em[((size_t)b*NS)*NT + tid];
    __syncthreads();
    for (int t = 1; t < NS; t++) {
        float nv = 0.f;
        if (tid < NT) {
            float m = -1e30f;
            for (int i = 0; i < NT; i++) m = fmaxf(m, sc[i] + tr[i][tid]);
            float s = 0.f;
            for (int i = 0; i < NT; i++) s += expf(sc[i] + tr[i][tid] - m);
            nv = m + logf(s) + em[((size_t)b*NS + t)*NT + tid];
        }
        __syncthreads();
        if (tid < NT) sc[tid] = nv;
        __syncthreads();
    }
    if (tid == 0) {
        float m = -1e30f;
        for (int j = 0; j < NT; j++) m = fmaxf(m, sc[j] + endv[j]);
        float s = 0.f;
        for (int j = 0; j < NT; j++) s += expf(sc[j] + endv[j] - m);
        float logZ = m + logf(s);
        const int* tg = tags + b*NS;
        float num = start[tg[0]] + em[((size_t)b*NS)*NT + tg[0]];
        for (int t = 1; t < NS; t++)
            num += tr[tg[t-1]][tg[t]] + em[((size_t)b*NS + t)*NT + tg[t]];
        num += endv[tg[NS-1]];
        partial[b] = -(num - logZ);
    }
}

__global__ void k_loss_final(const float* __restrict__ partial, float* __restrict__ loss)
{
    if (threadIdx.x == 0 && blockIdx.x == 0) {
        float s = 0.f;
        for (int b = 0; b < NB; b++) s += partial[b];
        *loss = s / (float)(NB*NS);
    }
}

extern "C" void kernel_launch(void* const* d_in, const int* in_sizes, int n_in,
                              void* d_out, int out_size, void* d_ws, size_t ws_size,
                              hipStream_t stream)
{
    const int*   x_word = (const int*)d_in[0];
    const float* x_pos  = (const float*)d_in[1];
    const int*   x_char = (const int*)d_in[2];
    const float* x_enr  = (const float*)d_in[3];
    const int*   y_word = (const int*)d_in[5];
    const float* wembW  = (const float*)d_in[6];
    const float* cembW  = (const float*)d_in[7];
    const float* cnnW   = (const float*)d_in[8];
    const float* cnnb   = (const float*)d_in[9];
    const float* lin1W  = (const float*)d_in[10];
    const float* lin1b  = (const float*)d_in[11];
    const float* lin2W  = (const float*)d_in[12];
    const float* lin2b  = (const float*)d_in[13];
    const float* crf_s  = (const float*)d_in[14];
    const float* crf_e  = (const float*)d_in[15];
    const float* crf_tr = (const float*)d_in[16];
    const float* l0f_Wih = (const float*)d_in[17];
    const float* l0f_Whh = (const float*)d_in[18];
    const float* l0f_b   = (const float*)d_in[19];
    const float* l0b_Wih = (const float*)d_in[20];
    const float* l0b_Whh = (const float*)d_in[21];
    const float* l0b_b   = (const float*)d_in[22];
    const float* l1f_Wih = (const float*)d_in[23];
    const float* l1f_Whh = (const float*)d_in[24];
    const float* l1f_b   = (const float*)d_in[25];
    const float* l1b_Wih = (const float*)d_in[26];
    const float* l1b_Whh = (const float*)d_in[27];
    const float* l1b_b   = (const float*)d_in[28];

    float* ws = (float*)d_ws;
    size_t off = 0;
    float* xw   = ws + off; off += (size_t)NBS*NIN0P;
    float* wpf  = ws + off; off += (size_t)NG4*NIN0P;
    float* wpb  = ws + off; off += (size_t)NG4*NIN0P;
    float* zxf  = ws + off; off += (size_t)NBS*NG4;
    float* zxb  = ws + off; off += (size_t)NBS*NG4;
    float* h0   = ws + off; off += (size_t)NBS*NIN1;
    float* h1   = ws + off; off += (size_t)NBS*NIN1;
    float* hid1 = ws + off; off += (size_t)NBS*NHID;
    float* partial = ws + off; off += 64;
    unsigned short* hbf = (unsigned short*)(ws + off); off += (size_t)(2*4*NB*NH)/2;  // bf16 hi+lo h ring
    unsigned* flags = (unsigned*)(ws + off); off += (size_t)2*NS*16;                  // sync counters

    float* em_out   = (float*)d_out;
    float* dec_out  = em_out + (size_t)NBS*NT;
    float* loss_out = dec_out + NBS;

    // 1. pad layer-0 input weights to K=336
    k_pad_wih<<<dim3((NG4*NIN0P+255)/256, 2), 256, 0, stream>>>(l0f_Wih, l0b_Wih, wpf, wpb);
    // 2. features
    k_features<<<NBS, 128, 0, stream>>>(x_word, x_pos, x_char, x_enr, wembW, cembW, cnnW, cnnb, xw);
    // 3. layer-0 input projections
    k_gemm<<<dim3(NBS/GBM, NG4/GBN), 256, 0, stream>>>(xw, wpf, l0f_b, zxf, NBS, NG4, NIN0P);
    k_gemm<<<dim3(NBS/GBM, NG4/GBN), 256, 0, stream>>>(xw, wpb, l0b_b, zxb, NBS, NG4, NIN0P);
    // 4. layer-0 recurrence (persistent, both dirs)
    hipMemsetAsync(flags, 0, (size_t)2*NS*16*sizeof(unsigned), stream);
    k_lstm_layer<<<dim3(NCHUNK, 2), 256, 0, stream>>>(zxf, zxb, l0f_Whh, l0b_Whh, h0, hbf, flags);
    // 5. layer-1 input projections
    k_gemm<<<dim3(NBS/GBM, NG4/GBN), 256, 0, stream>>>(h0, l1f_Wih, l1f_b, zxf, NBS, NG4, NIN1);
    k_gemm<<<dim3(NBS/GBM, NG4/GBN), 256, 0, stream>>>(h0, l1b_Wih, l1b_b, zxb, NBS, NG4, NIN1);
    // 6. layer-1 recurrence
    hipMemsetAsync(flags, 0, (size_t)2*NS*16*sizeof(unsigned), stream);
    k_lstm_layer<<<dim3(NCHUNK, 2), 256, 0, stream>>>(zxf, zxb, l1f_Whh, l1b_Whh, h1, hbf, flags);
    // 7. head
    k_gemm<<<dim3(NBS/GBM, NHID/GBN), 256, 0, stream>>>(h1, lin1W, lin1b, hid1, NBS, NHID, NIN1);
    k_lin2<<<(NBS*NT+255)/256, 256, 0, stream>>>(hid1, lin2W, lin2b, em_out);
    // 8. CRF
    k_viterbi<<<NB, 64, 0, stream>>>(em_out, crf_s, crf_e, crf_tr, dec_out);
    k_nll<<<NB, 64, 0, stream>>>(em_out, y_word, crf_s, crf_e, crf_tr, partial);
    k_loss_final<<<1, 64, 0, stream>>>(partial, loss_out);
}

// Round 4
// 9997.498 us; speedup vs baseline: 1.1699x; 1.1699x over previous
//
#include <hip/hip_runtime.h>
#include <hip/hip_bf16.h>
#include <math.h>

// ---- problem dims ----
constexpr int NB   = 32;     // batch
constexpr int NS   = 256;    // seq len
constexpr int NLC  = 16;     // chars per word
constexpr int NWD  = 256;    // word dim
constexpr int NCD  = 124;    // char dim
constexpr int NCO  = 32;     // cnn out
constexpr int NPOS = 36;
constexpr int NENR = 7;
constexpr int NH   = 512;    // lstm hidden
constexpr int NT   = 18;     // tags
constexpr int NIN0 = 331;    // 256+36+32+7
constexpr int NIN0P= 336;    // padded to x16
constexpr int NIN1 = 1024;
constexpr int NBS  = NB*NS;  // 8192
constexpr int NG4  = 4*NH;   // 2048
constexpr int NHID = 128;
constexpr int NCHUNK = 32;   // unit-chunks per dir (16 units each)

typedef __attribute__((ext_vector_type(8))) short short8v;
typedef __attribute__((ext_vector_type(4))) float f32x4;

__device__ __forceinline__ float sigmoidf_(float x){ return 1.0f/(1.0f+expf(-x)); }
__device__ __forceinline__ short f2bf(float f) {
    union { __hip_bfloat16 h; short s; } u;
    u.h = __float2bfloat16(f);
    return u.s;
}
__device__ __forceinline__ float bf2f(short s) {
    union { unsigned u; float f; } v;
    v.u = ((unsigned)(unsigned short)s) << 16;
    return v.f;
}

// ---------------- features: word embed + char CNN + concat + relu ----------------
__global__ __launch_bounds__(128) void k_features(const int* __restrict__ x_word,
    const float* __restrict__ x_pos, const int* __restrict__ x_char,
    const float* __restrict__ x_enr, const float* __restrict__ wembW,
    const float* __restrict__ cembW, const float* __restrict__ cnnW,
    const float* __restrict__ cnnb, float* __restrict__ xout)
{
    __shared__ float ce[NLC][NCD];
    __shared__ float cv[NCO][13];
    __shared__ float cpool[NCO];
    int n = blockIdx.x;
    int tid = threadIdx.x;
    for (int i = tid; i < NLC*NCD; i += 128) {
        int l = i / NCD, c = i % NCD;
        ce[l][c] = cembW[x_char[n*NLC + l]*NCD + c];
    }
    __syncthreads();
    for (int p = tid; p < NCO*12; p += 128) {
        int o = p & 31, t = p >> 5;
        const float* wr = cnnW + o*NCD*5;
        float acc = 0.f;
        for (int c = 0; c < NCD; c++) {
            #pragma unroll
            for (int k = 0; k < 5; k++) acc += ce[t+k][c] * wr[c*5+k];
        }
        cv[o][t] = acc;
    }
    __syncthreads();
    if (tid < NCO) {
        float m = cv[tid][0];
        #pragma unroll
        for (int t = 1; t < 12; t++) m = fmaxf(m, cv[tid][t]);
        cpool[tid] = m + cnnb[tid];
    }
    __syncthreads();
    int widx = x_word[n];
    float* xr = xout + (size_t)n * NIN0P;
    for (int j = tid; j < NIN0P; j += 128) {
        float v;
        if (j < NWD)            v = wembW[(size_t)widx*NWD + j];
        else if (j < NWD+NPOS)  v = x_pos[n*NPOS + (j-NWD)];
        else if (j < NWD+NPOS+NCO) v = cpool[j-(NWD+NPOS)];
        else if (j < NIN0)      v = x_enr[n*NENR + (j-(NWD+NPOS+NCO))];
        else                    v = 0.f;   // K pad
        xr[j] = fmaxf(v, 0.f);
    }
}

// ---------------- pad layer-0 Wih from K=331 to K=336 (zero tail) ----------------
__global__ void k_pad_wih(const float* __restrict__ Wf, const float* __restrict__ Wb,
                          float* __restrict__ Pf, float* __restrict__ Pb)
{
    const float* Wsrc = blockIdx.y ? Wb : Wf;
    float* Pdst = blockIdx.y ? Pb : Pf;
    int i = blockIdx.x*256 + threadIdx.x;
    if (i < NG4*NIN0P) {
        int r = i / NIN0P, c = i % NIN0P;
        Pdst[i] = (c < NIN0) ? Wsrc[r*NIN0 + c] : 0.f;
    }
}

// ---------------- f32 GEMM: C[M,N] = A[M,K] @ W[N,K]^T + bias[N] ----------------
constexpr int GBM = 128, GBN = 128, GBK = 16;
__global__ __launch_bounds__(256) void k_gemm(const float* __restrict__ A,
    const float* __restrict__ W, const float* __restrict__ bias,
    float* __restrict__ C, int M, int N, int K)
{
    __shared__ float As[GBK][GBM+4];
    __shared__ float Bs[GBK][GBN+4];
    int bm = blockIdx.x * GBM, bn = blockIdx.y * GBN;
    int tid = threadIdx.x;
    int tm = (tid & 15) * 8, tn = (tid >> 4) * 8;
    float acc[8][8] = {};
    for (int k0 = 0; k0 < K; k0 += GBK) {
        #pragma unroll
        for (int ii = 0; ii < 2; ii++) {
            int idx = tid + 256*ii;
            int m = idx >> 2, kj = (idx & 3) * 4;
            float4 va = *(const float4*)(A + (size_t)(bm+m)*K + k0 + kj);
            As[kj+0][m] = va.x; As[kj+1][m] = va.y; As[kj+2][m] = va.z; As[kj+3][m] = va.w;
            float4 vb = *(const float4*)(W + (size_t)(bn+m)*K + k0 + kj);
            Bs[kj+0][m] = vb.x; Bs[kj+1][m] = vb.y; Bs[kj+2][m] = vb.z; Bs[kj+3][m] = vb.w;
        }
        __syncthreads();
        #pragma unroll
        for (int k = 0; k < GBK; k++) {
            float a[8], b[8];
            *(float4*)&a[0] = *(const float4*)&As[k][tm];
            *(float4*)&a[4] = *(const float4*)&As[k][tm+4];
            *(float4*)&b[0] = *(const float4*)&Bs[k][tn];
            *(float4*)&b[4] = *(const float4*)&Bs[k][tn+4];
            #pragma unroll
            for (int i = 0; i < 8; i++)
                #pragma unroll
                for (int j = 0; j < 8; j++)
                    acc[i][j] += a[i]*b[j];
        }
        __syncthreads();
    }
    #pragma unroll
    for (int i = 0; i < 8; i++) {
        float4 o0, o1;
        o0.x = acc[i][0]+bias[bn+tn+0]; o0.y = acc[i][1]+bias[bn+tn+1];
        o0.z = acc[i][2]+bias[bn+tn+2]; o0.w = acc[i][3]+bias[bn+tn+3];
        o1.x = acc[i][4]+bias[bn+tn+4]; o1.y = acc[i][5]+bias[bn+tn+5];
        o1.z = acc[i][6]+bias[bn+tn+6]; o1.w = acc[i][7]+bias[bn+tn+7];
        *(float4*)(C + (size_t)(bm+tm+i)*N + bn+tn)   = o0;
        *(float4*)(C + (size_t)(bm+tm+i)*N + bn+tn+4) = o1;
    }
}

// ---------------- persistent LSTM layer (both dirs), weight-stationary MFMA ----
// grid (NCHUNK=32, 2 dirs), 256 threads (4 waves = 4 gates).
// Split-bf16 (bf16x3): z ~= h_hi*w_hi + h_lo*w_hi + h_hi*w_lo  (~2^-18 error).
// Latency engineering (round 4):
//  - zx prefetched into registers BEFORE the flag poll (independent of h)
//  - per-chunk release flags (no RMW contention), each wave polls all 32
//  - single release (wave 0) after barrier-drained stores; hcat store after it
//  - 6 independent MFMA accumulator chains
__global__ __launch_bounds__(256) void k_lstm_layer(
    const float* __restrict__ zx_f, const float* __restrict__ zx_b,
    const float* __restrict__ Whh_f, const float* __restrict__ Whh_b,
    float* __restrict__ hcat, unsigned short* __restrict__ hbf,
    unsigned* __restrict__ flags)
{
    int chunk = blockIdx.x;        // 0..31 (16 hidden units each)
    int dir   = blockIdx.y;
    int tid = threadIdx.x;
    int w  = tid >> 6;             // wave index = gate index (i,f,g,o)
    int l  = tid & 63;
    int lr = l & 15, lk = l >> 4;
    const float* zx  = dir ? zx_b  : zx_f;
    const float* Whh = dir ? Whh_b : Whh_f;
    // hb layout: [dir][slot 0/1][plane hi/lo][NB*NH]
    unsigned short* hb = hbf + (size_t)dir * (4*NB*NH);
    unsigned* flag = flags + (size_t)dir * NCHUNK * 16;   // 64B stride per chunk

    // ---- preload this wave's Whh slice into registers, split hi/lo bf16 ----
    short8v bwh[16], bwl[16];
    {
        const float* wrow = Whh + ((size_t)(w*NH + chunk*16 + lr))*NH + lk*8;
        #pragma unroll
        for (int kt = 0; kt < 16; kt++) {
            float u[8];
            *(float4*)&u[0] = *(const float4*)(wrow + kt*32);
            *(float4*)&u[4] = *(const float4*)(wrow + kt*32 + 4);
            short8v sh, sl;
            #pragma unroll
            for (int j = 0; j < 8; j++) {
                short hi = f2bf(u[j]);
                sh[j] = hi;
                sl[j] = f2bf(u[j] - bf2f(hi));
            }
            bwh[kt] = sh; bwl[kt] = sl;
        }
    }
    __shared__ float zsh[4][NB][16];
    float c0 = 0.f, c1 = 0.f;      // cell state: cells tid and tid+256

    for (int t = 0; t < NS; t++) {
        int t_eff = dir ? (NS-1-t) : t;

        // ---- prefetch zx for this step (independent of the flag) ----
        float pz[2][4];
        #pragma unroll
        for (int cc = 0; cc < 2; cc++) {
            int cell = tid + cc*256, b = cell >> 4, u = cell & 15;
            const float* zr = zx + ((size_t)(b*NS + t_eff))*NG4 + chunk*16 + u;
            #pragma unroll
            for (int g = 0; g < 4; g++) pz[cc][g] = zr[g*NH];
        }

        f32x4 a0hh = {0,0,0,0}, a0lh = {0,0,0,0}, a0hl = {0,0,0,0};
        f32x4 a1hh = {0,0,0,0}, a1lh = {0,0,0,0}, a1hl = {0,0,0,0};
        if (t > 0) {
            // ---- wave-parallel acquire poll on all 32 per-chunk flags ----
            {
                const unsigned* fp = &flag[(l & 31)*16];
                unsigned v;
                do {
                    v = __hip_atomic_load(fp, __ATOMIC_ACQUIRE,
                                          __HIP_MEMORY_SCOPE_AGENT);
                } while (!__all((int)(v >= (unsigned)t)));
            }
            const short* hph = (const short*)(hb + ((t-1)&1)*(2*NB*NH));  // hi plane
            const short* hpl = hph + NB*NH;                               // lo plane
            #pragma unroll
            for (int kt = 0; kt < 16; kt++) {
                int o0 = lr*NH      + kt*32 + lk*8;
                int o1 = (16+lr)*NH + kt*32 + lk*8;
                short8v a0h = *(const short8v*)(hph + o0);
                short8v a0l = *(const short8v*)(hpl + o0);
                short8v a1h = *(const short8v*)(hph + o1);
                short8v a1l = *(const short8v*)(hpl + o1);
                a0hh = __builtin_amdgcn_mfma_f32_16x16x32_bf16(a0h, bwh[kt], a0hh, 0, 0, 0);
                a0lh = __builtin_amdgcn_mfma_f32_16x16x32_bf16(a0l, bwh[kt], a0lh, 0, 0, 0);
                a0hl = __builtin_amdgcn_mfma_f32_16x16x32_bf16(a0h, bwl[kt], a0hl, 0, 0, 0);
                a1hh = __builtin_amdgcn_mfma_f32_16x16x32_bf16(a1h, bwh[kt], a1hh, 0, 0, 0);
                a1lh = __builtin_amdgcn_mfma_f32_16x16x32_bf16(a1l, bwh[kt], a1lh, 0, 0, 0);
                a1hl = __builtin_amdgcn_mfma_f32_16x16x32_bf16(a1h, bwl[kt], a1hl, 0, 0, 0);
            }
        }
        // C layout: col = lane&15 (unit), row = (lane>>4)*4+j (batch)
        #pragma unroll
        for (int j = 0; j < 4; j++) {
            zsh[w][lk*4+j][lr]    = a0hh[j] + a0lh[j] + a0hl[j];
            zsh[w][16+lk*4+j][lr] = a1hh[j] + a1lh[j] + a1hl[j];
        }
        __syncthreads();
        // ---- epilogue: 512 (batch,unit) cells / 256 threads ----
        float hn0, hn1;
        #pragma unroll
        for (int cc = 0; cc < 2; cc++) {
            int cell = tid + cc*256, b = cell >> 4, u = cell & 15;
            float zi = pz[cc][0] + zsh[0][b][u];
            float zf = pz[cc][1] + zsh[1][b][u];
            float zg = pz[cc][2] + zsh[2][b][u];
            float zo = pz[cc][3] + zsh[3][b][u];
            float cold = cc ? c1 : c0;
            float cn = sigmoidf_(zf)*cold + sigmoidf_(zi)*tanhf(zg);
            float hn = sigmoidf_(zo)*tanhf(cn);
            if (cc) { c1 = cn; hn1 = hn; } else { c0 = cn; hn0 = hn; }
            short hi = f2bf(hn);
            short lo = f2bf(hn - bf2f(hi));
            size_t slot = (size_t)(t&1)*(2*NB*NH) + b*NH + chunk*16 + u;
            hb[slot]         = (unsigned short)hi;
            hb[slot + NB*NH] = (unsigned short)lo;
        }
        // barrier drains all waves' hb stores to L2 (implicit vmcnt(0)) and
        // protects zsh (read above) from next iteration's overwrite
        __syncthreads();
        if (tid == 0)
            __hip_atomic_store(&flag[chunk*16], (unsigned)(t+1),
                               __ATOMIC_RELEASE, __HIP_MEMORY_SCOPE_AGENT);
        // hcat (f32, consumed only by later kernels) written after the release
        #pragma unroll
        for (int cc = 0; cc < 2; cc++) {
            int cell = tid + cc*256, b = cell >> 4, u = cell & 15;
            hcat[((size_t)(b*NS + t_eff))*NIN1 + dir*NH + chunk*16 + u] = cc ? hn1 : hn0;
        }
    }
}

// ---------------- emissions: em = hid1 @ lin2W^T + b2 ----------------
__global__ __launch_bounds__(256) void k_lin2(const float* __restrict__ hid,
    const float* __restrict__ W2, const float* __restrict__ b2, float* __restrict__ em)
{
    int flat = blockIdx.x*256 + threadIdx.x;
    if (flat >= NBS*NT) return;
    int m = flat / NT, j = flat % NT;
    const float* hr = hid + (size_t)m*NHID;
    const float* wr = W2 + j*NHID;
    float acc = b2[j];
    #pragma unroll 8
    for (int k = 0; k < NHID; k += 4) {
        float4 h4 = *(const float4*)(hr+k);
        float4 w4 = *(const float4*)(wr+k);
        acc += h4.x*w4.x + h4.y*w4.y + h4.z*w4.z + h4.w*w4.w;
    }
    em[flat] = acc;
}

// ---------------- viterbi decode (one wave per batch item) ----------------
__global__ __launch_bounds__(64) void k_viterbi(const float* __restrict__ em,
    const float* __restrict__ start, const float* __restrict__ endv,
    const float* __restrict__ trans, float* __restrict__ dec)
{
    __shared__ float sc[NT];
    __shared__ float tr[NT][NT];
    __shared__ unsigned char hist[NS][NT];
    int b = blockIdx.x, tid = threadIdx.x;
    for (int i = tid; i < NT*NT; i += 64) tr[i/NT][i%NT] = trans[i];
    if (tid < NT) sc[tid] = start[tid] + em[((size_t)b*NS)*NT + tid];
    __syncthreads();
    for (int t = 1; t < NS; t++) {
        float best = -1e30f; int bi = 0;
        if (tid < NT) {
            for (int i = 0; i < NT; i++) {
                float v = sc[i] + tr[i][tid];
                if (v > best) { best = v; bi = i; }
            }
            hist[t][tid] = (unsigned char)bi;
            best += em[((size_t)b*NS + t)*NT + tid];
        }
        __syncthreads();
        if (tid < NT) sc[tid] = best;
        __syncthreads();
    }
    if (tid == 0) {
        float bv = sc[0] + endv[0]; int tag = 0;
        for (int j = 1; j < NT; j++) { float v = sc[j] + endv[j]; if (v > bv) { bv = v; tag = j; } }
        dec[b*NS + NS-1] = (float)tag;
        for (int t = NS-1; t >= 1; t--) { tag = hist[t][tag]; dec[b*NS + t-1] = (float)tag; }
    }
}

// ---------------- CRF NLL (mask is all ones) ----------------
__global__ __launch_bounds__(64) void k_nll(const float* __restrict__ em,
    const int* __restrict__ tags, const float* __restrict__ start,
    const float* __restrict__ endv, const float* __restrict__ trans,
    float* __restrict__ partial)
{
    __shared__ float sc[NT];
    __shared__ float tr[NT][NT];
    int b = blockIdx.x, tid = threadIdx.x;
    for (int i = tid; i < NT*NT; i += 64) tr[i/NT][i%NT] = trans[i];
    if (tid < NT) sc[tid] = start[tid] + em[((size_t)b*NS)*NT + tid];
    __syncthreads();
    for (int t = 1; t < NS; t++) {
        float nv = 0.f;
        if (tid < NT) {
            float m = -1e30f;
            for (int i = 0; i < NT; i++) m = fmaxf(m, sc[i] + tr[i][tid]);
            float s = 0.f;
            for (int i = 0; i < NT; i++) s += expf(sc[i] + tr[i][tid] - m);
            nv = m + logf(s) + em[((size_t)b*NS + t)*NT + tid];
        }
        __syncthreads();
        if (tid < NT) sc[tid] = nv;
        __syncthreads();
    }
    if (tid == 0) {
        float m = -1e30f;
        for (int j = 0; j < NT; j++) m = fmaxf(m, sc[j] + endv[j]);
        float s = 0.f;
        for (int j = 0; j < NT; j++) s += expf(sc[j] + endv[j] - m);
        float logZ = m + logf(s);
        const int* tg = tags + b*NS;
        float num = start[tg[0]] + em[((size_t)b*NS)*NT + tg[0]];
        for (int t = 1; t < NS; t++)
            num += tr[tg[t-1]][tg[t]] + em[((size_t)b*NS + t)*NT + tg[t]];
        num += endv[tg[NS-1]];
        partial[b] = -(num - logZ);
    }
}

__global__ void k_loss_final(const float* __restrict__ partial, float* __restrict__ loss)
{
    if (threadIdx.x == 0 && blockIdx.x == 0) {
        float s = 0.f;
        for (int b = 0; b < NB; b++) s += partial[b];
        *loss = s / (float)(NB*NS);
    }
}

extern "C" void kernel_launch(void* const* d_in, const int* in_sizes, int n_in,
                              void* d_out, int out_size, void* d_ws, size_t ws_size,
                              hipStream_t stream)
{
    const int*   x_word = (const int*)d_in[0];
    const float* x_pos  = (const float*)d_in[1];
    const int*   x_char = (const int*)d_in[2];
    const float* x_enr  = (const float*)d_in[3];
    const int*   y_word = (const int*)d_in[5];
    const float* wembW  = (const float*)d_in[6];
    const float* cembW  = (const float*)d_in[7];
    const float* cnnW   = (const float*)d_in[8];
    const float* cnnb   = (const float*)d_in[9];
    const float* lin1W  = (const float*)d_in[10];
    const float* lin1b  = (const float*)d_in[11];
    const float* lin2W  = (const float*)d_in[12];
    const float* lin2b  = (const float*)d_in[13];
    const float* crf_s  = (const float*)d_in[14];
    const float* crf_e  = (const float*)d_in[15];
    const float* crf_tr = (const float*)d_in[16];
    const float* l0f_Wih = (const float*)d_in[17];
    const float* l0f_Whh = (const float*)d_in[18];
    const float* l0f_b   = (const float*)d_in[19];
    const float* l0b_Wih = (const float*)d_in[20];
    const float* l0b_Whh = (const float*)d_in[21];
    const float* l0b_b   = (const float*)d_in[22];
    const float* l1f_Wih = (const float*)d_in[23];
    const float* l1f_Whh = (const float*)d_in[24];
    const float* l1f_b   = (const float*)d_in[25];
    const float* l1b_Wih = (const float*)d_in[26];
    const float* l1b_Whh = (const float*)d_in[27];
    const float* l1b_b   = (const float*)d_in[28];

    float* ws = (float*)d_ws;
    size_t off = 0;
    float* xw   = ws + off; off += (size_t)NBS*NIN0P;
    float* wpf  = ws + off; off += (size_t)NG4*NIN0P;
    float* wpb  = ws + off; off += (size_t)NG4*NIN0P;
    float* zxf  = ws + off; off += (size_t)NBS*NG4;
    float* zxb  = ws + off; off += (size_t)NBS*NG4;
    float* h0   = ws + off; off += (size_t)NBS*NIN1;
    float* h1   = ws + off; off += (size_t)NBS*NIN1;
    float* hid1 = ws + off; off += (size_t)NBS*NHID;
    float* partial = ws + off; off += 64;
    unsigned short* hbf = (unsigned short*)(ws + off); off += (size_t)(2*4*NB*NH)/2;  // bf16 hi+lo h ring
    unsigned* flags = (unsigned*)(ws + off); off += (size_t)2*NCHUNK*16;              // per-chunk flags

    float* em_out   = (float*)d_out;
    float* dec_out  = em_out + (size_t)NBS*NT;
    float* loss_out = dec_out + NBS;

    // 1. pad layer-0 input weights to K=336
    k_pad_wih<<<dim3((NG4*NIN0P+255)/256, 2), 256, 0, stream>>>(l0f_Wih, l0b_Wih, wpf, wpb);
    // 2. features
    k_features<<<NBS, 128, 0, stream>>>(x_word, x_pos, x_char, x_enr, wembW, cembW, cnnW, cnnb, xw);
    // 3. layer-0 input projections
    k_gemm<<<dim3(NBS/GBM, NG4/GBN), 256, 0, stream>>>(xw, wpf, l0f_b, zxf, NBS, NG4, NIN0P);
    k_gemm<<<dim3(NBS/GBM, NG4/GBN), 256, 0, stream>>>(xw, wpb, l0b_b, zxb, NBS, NG4, NIN0P);
    // 4. layer-0 recurrence (persistent, both dirs)
    hipMemsetAsync(flags, 0, (size_t)2*NCHUNK*16*sizeof(unsigned), stream);
    k_lstm_layer<<<dim3(NCHUNK, 2), 256, 0, stream>>>(zxf, zxb, l0f_Whh, l0b_Whh, h0, hbf, flags);
    // 5. layer-1 input projections
    k_gemm<<<dim3(NBS/GBM, NG4/GBN), 256, 0, stream>>>(h0, l1f_Wih, l1f_b, zxf, NBS, NG4, NIN1);
    k_gemm<<<dim3(NBS/GBM, NG4/GBN), 256, 0, stream>>>(h0, l1b_Wih, l1b_b, zxb, NBS, NG4, NIN1);
    // 6. layer-1 recurrence
    hipMemsetAsync(flags, 0, (size_t)2*NCHUNK*16*sizeof(unsigned), stream);
    k_lstm_layer<<<dim3(NCHUNK, 2), 256, 0, stream>>>(zxf, zxb, l1f_Whh, l1b_Whh, h1, hbf, flags);
    // 7. head
    k_gemm<<<dim3(NBS/GBM, NHID/GBN), 256, 0, stream>>>(h1, lin1W, lin1b, hid1, NBS, NHID, NIN1);
    k_lin2<<<(NBS*NT+255)/256, 256, 0, stream>>>(hid1, lin2W, lin2b, em_out);
    // 8. CRF
    k_viterbi<<<NB, 64, 0, stream>>>(em_out, crf_s, crf_e, crf_tr, dec_out);
    k_nll<<<NB, 64, 0, stream>>>(em_out, y_word, crf_s, crf_e, crf_tr, partial);
    k_loss_final<<<1, 64, 0, stream>>>(partial, loss_out);
}